// Round 1
// baseline (1064.817 us; speedup 1.0000x reference)
//
#include <hip/hip_runtime.h>
#include <math.h>

#define BATCH 2
#define SEQ   1024
#define DM    1024
#define DI    2048
#define DS    16
#define DTR   64
#define ROWS  (BATCH*SEQ)   // 2048

// ---------------------------------------------------------------------------
// Generic tiled fp32 GEMM: C[M,N] = act(A[M,K] @ B[K,N] + bias)
// A row-major (lda), B row-major (ldb), C row-major (ldc).
// ACT: 0 = none, 1 = softplus
// Requires: M % 64 == 0, K % 16 == 0. N guarded.
// ---------------------------------------------------------------------------
template<int ACT>
__global__ __launch_bounds__(256) void gemm_f32(
    const float* __restrict__ A, int lda,
    const float* __restrict__ B, int ldb,
    float* __restrict__ C, int ldc,
    int M, int N, int K,
    const float* __restrict__ bias)
{
    const int BM = 64, BN = 64, BK = 16;
    __shared__ float As[BK][BM];
    __shared__ float Bs[BK][BN];

    int tid  = threadIdx.x;
    int row0 = blockIdx.y * BM;
    int col0 = blockIdx.x * BN;
    int tx = tid & 15;       // 0..15 -> col group
    int ty = tid >> 4;       // 0..15 -> row group

    int ar = tid >> 2;        // 0..63  A tile row
    int ac = (tid & 3) * 4;   // 0,4,8,12  A tile col base
    int br = tid >> 4;        // 0..15  B tile row
    int bc = (tid & 15) * 4;  // 0..60  B tile col base

    float acc[4][4] = {};

    for (int k0 = 0; k0 < K; k0 += BK) {
        #pragma unroll
        for (int j = 0; j < 4; ++j)
            As[ac + j][ar] = A[(size_t)(row0 + ar) * lda + k0 + ac + j];
        #pragma unroll
        for (int j = 0; j < 4; ++j) {
            int c = col0 + bc + j;
            Bs[br][bc + j] = (c < N) ? B[(size_t)(k0 + br) * ldb + c] : 0.f;
        }
        __syncthreads();
        #pragma unroll
        for (int k = 0; k < BK; ++k) {
            float4 a4 = *(const float4*)&As[k][ty * 4];
            float4 b4 = *(const float4*)&Bs[k][tx * 4];
            float av[4] = {a4.x, a4.y, a4.z, a4.w};
            float bv[4] = {b4.x, b4.y, b4.z, b4.w};
            #pragma unroll
            for (int i = 0; i < 4; ++i)
                #pragma unroll
                for (int j = 0; j < 4; ++j)
                    acc[i][j] = fmaf(av[i], bv[j], acc[i][j]);
        }
        __syncthreads();
    }

    #pragma unroll
    for (int i = 0; i < 4; ++i) {
        int r = row0 + ty * 4 + i;
        #pragma unroll
        for (int j = 0; j < 4; ++j) {
            int c = col0 + tx * 4 + j;
            if (c < N) {
                float v = acc[i][j];
                if (bias) v += bias[c];
                if (ACT == 1) v = (v > 20.f) ? v : log1pf(expf(v));
                C[(size_t)r * ldc + c] = v;
            }
        }
    }
}

// ---------------------------------------------------------------------------
// Depthwise causal conv (k=3) + SiLU.
// xw: [ROWS, 4096], u part = cols 0..2047. out u: [ROWS, DI]
// ---------------------------------------------------------------------------
__global__ __launch_bounds__(256) void conv_silu_kernel(
    const float* __restrict__ xw,
    const float* __restrict__ Wc,     // [DI,3]
    float* __restrict__ u)
{
    int idx = blockIdx.x * 256 + threadIdx.x;   // over ROWS*DI
    if (idx >= ROWS * DI) return;
    int d = idx & (DI - 1);
    int r = idx >> 11;
    int l = r & (SEQ - 1);
    float w0 = Wc[d * 3 + 0], w1 = Wc[d * 3 + 1], w2 = Wc[d * 3 + 2];
    const float* base = xw + (size_t)r * 4096 + d;
    float v = w2 * base[0];
    if (l >= 1) v += w1 * base[-4096];
    if (l >= 2) v += w0 * base[-8192];
    v = v / (1.f + expf(-v));     // silu
    u[(size_t)r * DI + d] = v;
}

// ---------------------------------------------------------------------------
// Selective scan. One thread per (b, d, n). 16-lane groups per channel.
// delta: [ROWS, DI], u: [ROWS, DI], xdbl: [ROWS, 96] (B at col 64, C at 80)
// y written to ybuf with stride 4096 (reusing dead u_pre half of buf0).
// ---------------------------------------------------------------------------
__global__ __launch_bounds__(256) void scan_kernel(
    const float* __restrict__ delta,
    const float* __restrict__ u,
    const float* __restrict__ xdbl,
    const float* __restrict__ A_log,
    float* __restrict__ ybuf)
{
    int gtid = blockIdx.x * 256 + threadIdx.x;    // 0 .. BATCH*DI*DS-1
    int n = gtid & (DS - 1);
    int c = gtid >> 4;           // channel index 0..4095
    int d = c & (DI - 1);
    int b = c >> 11;

    float A = -expf(A_log[d * DS + n]);
    float h = 0.f;

    const float* drow = delta + (size_t)b * SEQ * DI + d;
    const float* urow = u     + (size_t)b * SEQ * DI + d;
    const float* xrow = xdbl  + (size_t)b * SEQ * 96;
    float* yrow = ybuf + (size_t)b * SEQ * 4096 + d;

    for (int l = 0; l < SEQ; ++l) {
        float dv = drow[(size_t)l * DI];
        float uv = urow[(size_t)l * DI];
        float Bn = xrow[l * 96 + 64 + n];
        float Cn = xrow[l * 96 + 80 + n];
        h = __expf(dv * A) * h + dv * uv * Bn;
        float p = h * Cn;
        p += __shfl_xor(p, 1);
        p += __shfl_xor(p, 2);
        p += __shfl_xor(p, 4);
        p += __shfl_xor(p, 8);
        if (n == 0) yrow[(size_t)l * 4096] = p;
    }
}

// ---------------------------------------------------------------------------
// y_final = (y_ssm + u*D) * silu(res); res = xw cols 2048..4095
// ---------------------------------------------------------------------------
__global__ __launch_bounds__(256) void combine_kernel(
    const float* __restrict__ buf0,    // y_ssm at col d, res at col 2048+d
    const float* __restrict__ u,
    const float* __restrict__ Dp,
    float* __restrict__ yf)
{
    int idx = blockIdx.x * 256 + threadIdx.x;
    if (idx >= ROWS * DI) return;
    int d = idx & (DI - 1);
    int r = idx >> 11;
    float ys = buf0[(size_t)r * 4096 + d];
    float rs = buf0[(size_t)r * 4096 + 2048 + d];
    float uv = u[(size_t)r * DI + d];
    float v = (ys + uv * Dp[d]) * (rs / (1.f + expf(-rs)));
    yf[(size_t)r * DI + d] = v;
}

extern "C" void kernel_launch(void* const* d_in, const int* in_sizes, int n_in,
                              void* d_out, int out_size, void* d_ws, size_t ws_size,
                              hipStream_t stream) {
    const float* x       = (const float*)d_in[0];
    const float* W_in    = (const float*)d_in[1];
    const float* W_conv  = (const float*)d_in[2];
    const float* W_x     = (const float*)d_in[3];
    const float* W_dt    = (const float*)d_in[4];
    const float* b_dt    = (const float*)d_in[5];
    const float* A_log   = (const float*)d_in[6];
    const float* D_param = (const float*)d_in[7];
    const float* W_out   = (const float*)d_in[8];
    float* out = (float*)d_out;

    float* buf0 = (float*)d_ws;                       // [ROWS,4096] xW_in, later y_ssm in cols 0..2047
    float* buf1 = buf0 + (size_t)ROWS * 4096;         // [ROWS,DI]   u
    float* buf2 = buf1 + (size_t)ROWS * DI;           // [ROWS,96]   x_dbl
    float* buf3 = buf2 + (size_t)ROWS * 96;           // [ROWS,DI]   delta -> y_final

    dim3 blk(256);

    // G1: xW_in = x @ W_in   [2048 x 4096]
    gemm_f32<0><<<dim3((2 * DI) / 64, ROWS / 64), blk, 0, stream>>>(
        x, DM, W_in, 2 * DI, buf0, 2 * DI, ROWS, 2 * DI, DM, nullptr);

    // conv + silu -> u
    conv_silu_kernel<<<(ROWS * DI) / 256, blk, 0, stream>>>(buf0, W_conv, buf1);

    // G2: x_dbl = u @ W_x   [2048 x 96]
    gemm_f32<0><<<dim3((96 + 63) / 64, ROWS / 64), blk, 0, stream>>>(
        buf1, DI, W_x, 96, buf2, 96, ROWS, 96, DI, nullptr);

    // G3: delta = softplus(dt @ W_dt + b_dt)   [2048 x 2048], K=64, A = x_dbl cols 0..63
    gemm_f32<1><<<dim3(DI / 64, ROWS / 64), blk, 0, stream>>>(
        buf2, 96, W_dt, DI, buf3, DI, ROWS, DI, DTR, b_dt);

    // scan -> y_ssm (into buf0 cols 0..2047, stride 4096)
    scan_kernel<<<(BATCH * DI * DS) / 256, blk, 0, stream>>>(
        buf3, buf1, buf2, A_log, buf0);

    // combine -> y_final (overwrites delta in buf3)
    combine_kernel<<<(ROWS * DI) / 256, blk, 0, stream>>>(buf0, buf1, D_param, buf3);

    // G4: out = y_final @ W_out   [2048 x 1024]
    gemm_f32<0><<<dim3(DM / 64, ROWS / 64), blk, 0, stream>>>(
        buf3, DI, W_out, DM, out, DM, ROWS, DM, DI, nullptr);
}

// Round 2
// 710.879 us; speedup vs baseline: 1.4979x; 1.4979x over previous
//
#include <hip/hip_runtime.h>
#include <math.h>

#define BATCH 2
#define SEQ   1024
#define DM    1024
#define DI    2048
#define DS    16
#define DTR   64
#define ROWS  (BATCH*SEQ)   // 2048
#define CH    32            // chunk length for parallel scan
#define NCH   (SEQ/CH)      // 32 chunks

// ---------------------------------------------------------------------------
// Generic tiled fp32 GEMM: C[M,N] = act(A[M,K] @ B[K,N] + bias)
// ACT: 0 = none, 1 = softplus
// ---------------------------------------------------------------------------
template<int ACT>
__global__ __launch_bounds__(256) void gemm_f32(
    const float* __restrict__ A, int lda,
    const float* __restrict__ B, int ldb,
    float* __restrict__ C, int ldc,
    int M, int N, int K,
    const float* __restrict__ bias)
{
    const int BM = 64, BN = 64, BK = 16;
    __shared__ float As[BK][BM];
    __shared__ float Bs[BK][BN];

    int tid  = threadIdx.x;
    int row0 = blockIdx.y * BM;
    int col0 = blockIdx.x * BN;
    int tx = tid & 15;
    int ty = tid >> 4;

    int ar = tid >> 2;
    int ac = (tid & 3) * 4;
    int br = tid >> 4;
    int bc = (tid & 15) * 4;

    float acc[4][4] = {};

    for (int k0 = 0; k0 < K; k0 += BK) {
        #pragma unroll
        for (int j = 0; j < 4; ++j)
            As[ac + j][ar] = A[(size_t)(row0 + ar) * lda + k0 + ac + j];
        #pragma unroll
        for (int j = 0; j < 4; ++j) {
            int c = col0 + bc + j;
            Bs[br][bc + j] = (c < N) ? B[(size_t)(k0 + br) * ldb + c] : 0.f;
        }
        __syncthreads();
        #pragma unroll
        for (int k = 0; k < BK; ++k) {
            float4 a4 = *(const float4*)&As[k][ty * 4];
            float4 b4 = *(const float4*)&Bs[k][tx * 4];
            float av[4] = {a4.x, a4.y, a4.z, a4.w};
            float bv[4] = {b4.x, b4.y, b4.z, b4.w};
            #pragma unroll
            for (int i = 0; i < 4; ++i)
                #pragma unroll
                for (int j = 0; j < 4; ++j)
                    acc[i][j] = fmaf(av[i], bv[j], acc[i][j]);
        }
        __syncthreads();
    }

    #pragma unroll
    for (int i = 0; i < 4; ++i) {
        int r = row0 + ty * 4 + i;
        #pragma unroll
        for (int j = 0; j < 4; ++j) {
            int c = col0 + tx * 4 + j;
            if (c < N) {
                float v = acc[i][j];
                if (bias) v += bias[c];
                if (ACT == 1) v = (v > 20.f) ? v : log1pf(expf(v));
                C[(size_t)r * ldc + c] = v;
            }
        }
    }
}

// ---------------------------------------------------------------------------
// Depthwise causal conv (k=3) + SiLU.
// ---------------------------------------------------------------------------
__global__ __launch_bounds__(256) void conv_silu_kernel(
    const float* __restrict__ xw,
    const float* __restrict__ Wc,
    float* __restrict__ u)
{
    int idx = blockIdx.x * 256 + threadIdx.x;
    if (idx >= ROWS * DI) return;
    int d = idx & (DI - 1);
    int r = idx >> 11;
    int l = r & (SEQ - 1);
    float w0 = Wc[d * 3 + 0], w1 = Wc[d * 3 + 1], w2 = Wc[d * 3 + 2];
    const float* base = xw + (size_t)r * 4096 + d;
    float v = w2 * base[0];
    if (l >= 1) v += w1 * base[-4096];
    if (l >= 2) v += w0 * base[-8192];
    v = v / (1.f + expf(-v));
    u[(size_t)r * DI + d] = v;
}

// ---------------------------------------------------------------------------
// Scan pass A: per (b, chunk, d) thread, all 16 n-states in registers.
// Computes P = prod(dA) and Q = local h (starting from 0) over the chunk.
// Layout of P/Q: [(b*NCH+chunk)*DI + d] * DS + n
// ---------------------------------------------------------------------------
__global__ __launch_bounds__(256) void scan_chunk_kernel(
    const float* __restrict__ delta,
    const float* __restrict__ u,
    const float* __restrict__ xdbl,
    const float* __restrict__ A_log,
    float* __restrict__ P,
    float* __restrict__ Q)
{
    int idx = blockIdx.x * 256 + threadIdx.x;   // B*NCH*DI = 131072
    int d = idx & (DI - 1);
    int rc = idx >> 11;
    int chunk = rc & (NCH - 1);
    int b = rc >> 5;

    float Av[DS], h[DS], Pp[DS];
    #pragma unroll
    for (int q = 0; q < 4; ++q) {
        float4 a4 = *(const float4*)(A_log + (size_t)d * DS + q * 4);
        Av[q*4+0] = -__expf(a4.x); Av[q*4+1] = -__expf(a4.y);
        Av[q*4+2] = -__expf(a4.z); Av[q*4+3] = -__expf(a4.w);
    }
    #pragma unroll
    for (int n = 0; n < DS; ++n) { h[n] = 0.f; Pp[n] = 1.f; }

    int l0 = chunk * CH;
    const float* drow = delta + ((size_t)b * SEQ + l0) * DI + d;
    const float* urow = u     + ((size_t)b * SEQ + l0) * DI + d;
    const float* xrow = xdbl  + ((size_t)b * SEQ + l0) * 96 + 64;

    #pragma unroll 4
    for (int l = 0; l < CH; ++l) {
        float dv = drow[(size_t)l * DI];
        float du = dv * urow[(size_t)l * DI];
        float Bv[DS];
        #pragma unroll
        for (int q = 0; q < 4; ++q) {
            float4 b4 = *(const float4*)(xrow + l * 96 + q * 4);
            Bv[q*4+0] = b4.x; Bv[q*4+1] = b4.y; Bv[q*4+2] = b4.z; Bv[q*4+3] = b4.w;
        }
        #pragma unroll
        for (int n = 0; n < DS; ++n) {
            float dA = __expf(dv * Av[n]);
            h[n] = dA * h[n] + du * Bv[n];
            Pp[n] *= dA;
        }
    }
    float* Pd = P + (size_t)idx * DS;
    float* Qd = Q + (size_t)idx * DS;
    #pragma unroll
    for (int n = 0; n < DS; ++n) { Pd[n] = Pp[n]; Qd[n] = h[n]; }
}

// ---------------------------------------------------------------------------
// Scan pass B: sequential combine over chunks. h_in[chunk] per (b,d,n).
// ---------------------------------------------------------------------------
__global__ __launch_bounds__(256) void scan_combine_kernel(
    const float* __restrict__ P,
    const float* __restrict__ Q,
    float* __restrict__ hin)
{
    int idx = blockIdx.x * 256 + threadIdx.x;    // B*DI*DS = 65536
    int nd = idx & (DI * DS - 1);
    int b = idx >> 15;
    float h = 0.f;
    for (int c = 0; c < NCH; ++c) {
        size_t off = (size_t)(b * NCH + c) * DI * DS + nd;
        hin[off] = h;
        h = P[off] * h + Q[off];
    }
}

// ---------------------------------------------------------------------------
// Scan pass C: re-run local scan with correct h_in, emit y (sum over n).
// y written to ybuf (buf0 cols 0..2047, row stride 4096).
// ---------------------------------------------------------------------------
__global__ __launch_bounds__(256) void scan_final_kernel(
    const float* __restrict__ delta,
    const float* __restrict__ u,
    const float* __restrict__ xdbl,
    const float* __restrict__ A_log,
    const float* __restrict__ hin,
    float* __restrict__ ybuf)
{
    int idx = blockIdx.x * 256 + threadIdx.x;   // B*NCH*DI
    int d = idx & (DI - 1);
    int rc = idx >> 11;
    int chunk = rc & (NCH - 1);
    int b = rc >> 5;

    float Av[DS], h[DS];
    #pragma unroll
    for (int q = 0; q < 4; ++q) {
        float4 a4 = *(const float4*)(A_log + (size_t)d * DS + q * 4);
        Av[q*4+0] = -__expf(a4.x); Av[q*4+1] = -__expf(a4.y);
        Av[q*4+2] = -__expf(a4.z); Av[q*4+3] = -__expf(a4.w);
    }
    const float* hsrc = hin + (size_t)idx * DS;
    #pragma unroll
    for (int n = 0; n < DS; ++n) h[n] = hsrc[n];

    int l0 = chunk * CH;
    const float* drow = delta + ((size_t)b * SEQ + l0) * DI + d;
    const float* urow = u     + ((size_t)b * SEQ + l0) * DI + d;
    const float* xrow = xdbl  + ((size_t)b * SEQ + l0) * 96 + 64;
    float* yrow = ybuf + ((size_t)b * SEQ + l0) * 4096 + d;

    #pragma unroll 4
    for (int l = 0; l < CH; ++l) {
        float dv = drow[(size_t)l * DI];
        float du = dv * urow[(size_t)l * DI];
        float Bv[DS], Cv[DS];
        #pragma unroll
        for (int q = 0; q < 4; ++q) {
            float4 b4 = *(const float4*)(xrow + l * 96 + q * 4);
            Bv[q*4+0] = b4.x; Bv[q*4+1] = b4.y; Bv[q*4+2] = b4.z; Bv[q*4+3] = b4.w;
            float4 c4 = *(const float4*)(xrow + l * 96 + 16 + q * 4);
            Cv[q*4+0] = c4.x; Cv[q*4+1] = c4.y; Cv[q*4+2] = c4.z; Cv[q*4+3] = c4.w;
        }
        float y = 0.f;
        #pragma unroll
        for (int n = 0; n < DS; ++n) {
            float dA = __expf(dv * Av[n]);
            h[n] = dA * h[n] + du * Bv[n];
            y = fmaf(h[n], Cv[n], y);
        }
        yrow[(size_t)l * 4096] = y;
    }
}

// ---------------------------------------------------------------------------
// y_final = (y_ssm + u*D) * silu(res)
// ---------------------------------------------------------------------------
__global__ __launch_bounds__(256) void combine_kernel(
    const float* __restrict__ buf0,
    const float* __restrict__ u,
    const float* __restrict__ Dp,
    float* __restrict__ yf)
{
    int idx = blockIdx.x * 256 + threadIdx.x;
    if (idx >= ROWS * DI) return;
    int d = idx & (DI - 1);
    int r = idx >> 11;
    float ys = buf0[(size_t)r * 4096 + d];
    float rs = buf0[(size_t)r * 4096 + 2048 + d];
    float uv = u[(size_t)r * DI + d];
    float v = (ys + uv * Dp[d]) * (rs / (1.f + expf(-rs)));
    yf[(size_t)r * DI + d] = v;
}

extern "C" void kernel_launch(void* const* d_in, const int* in_sizes, int n_in,
                              void* d_out, int out_size, void* d_ws, size_t ws_size,
                              hipStream_t stream) {
    const float* x       = (const float*)d_in[0];
    const float* W_in    = (const float*)d_in[1];
    const float* W_conv  = (const float*)d_in[2];
    const float* W_x     = (const float*)d_in[3];
    const float* W_dt    = (const float*)d_in[4];
    const float* b_dt    = (const float*)d_in[5];
    const float* A_log   = (const float*)d_in[6];
    const float* D_param = (const float*)d_in[7];
    const float* W_out   = (const float*)d_in[8];
    float* out = (float*)d_out;

    float* buf0 = (float*)d_ws;                       // [ROWS,4096] xW_in; y_ssm in cols 0..2047
    float* buf1 = buf0 + (size_t)ROWS * 4096;         // [ROWS,DI]   u
    float* buf2 = buf1 + (size_t)ROWS * DI;           // [ROWS,96]   x_dbl
    float* buf3 = buf2 + (size_t)ROWS * 96;           // [ROWS,DI]   delta -> y_final
    float* Pbuf = buf3 + (size_t)ROWS * DI;           // [B*NCH*DI, DS]
    float* Qbuf = Pbuf + (size_t)BATCH * NCH * DI * DS;
    float* Hbuf = Qbuf + (size_t)BATCH * NCH * DI * DS;

    dim3 blk(256);

    // G1: xW_in = x @ W_in   [2048 x 4096]
    gemm_f32<0><<<dim3((2 * DI) / 64, ROWS / 64), blk, 0, stream>>>(
        x, DM, W_in, 2 * DI, buf0, 2 * DI, ROWS, 2 * DI, DM, nullptr);

    // conv + silu -> u
    conv_silu_kernel<<<(ROWS * DI) / 256, blk, 0, stream>>>(buf0, W_conv, buf1);

    // G2: x_dbl = u @ W_x   [2048 x 96]
    gemm_f32<0><<<dim3((96 + 63) / 64, ROWS / 64), blk, 0, stream>>>(
        buf1, DI, W_x, 96, buf2, 96, ROWS, 96, DI, nullptr);

    // G3: delta = softplus(dt @ W_dt + b_dt)   [2048 x 2048], K=64
    gemm_f32<1><<<dim3(DI / 64, ROWS / 64), blk, 0, stream>>>(
        buf2, 96, W_dt, DI, buf3, DI, ROWS, DI, DTR, b_dt);

    // scan pass A: chunk-local (P, Q)
    scan_chunk_kernel<<<(BATCH * NCH * DI) / 256, blk, 0, stream>>>(
        buf3, buf1, buf2, A_log, Pbuf, Qbuf);

    // scan pass B: combine chunks -> h_in
    scan_combine_kernel<<<(BATCH * DI * DS) / 256, blk, 0, stream>>>(
        Pbuf, Qbuf, Hbuf);

    // scan pass C: final local scan + y emit
    scan_final_kernel<<<(BATCH * NCH * DI) / 256, blk, 0, stream>>>(
        buf3, buf1, buf2, A_log, Hbuf, buf0);

    // combine -> y_final
    combine_kernel<<<(ROWS * DI) / 256, blk, 0, stream>>>(buf0, buf1, D_param, buf3);

    // G4: out = y_final @ W_out   [2048 x 1024]
    gemm_f32<0><<<dim3(DM / 64, ROWS / 64), blk, 0, stream>>>(
        buf3, DI, W_out, DM, out, DM, ROWS, DM, DI, nullptr);
}

// Round 3
// 243.137 us; speedup vs baseline: 4.3795x; 2.9238x over previous
//
#include <hip/hip_runtime.h>
#include <math.h>
#include <stdint.h>

#define BATCH 2
#define SEQ   1024
#define DM    1024
#define DI    2048
#define DS    16
#define DTR   64
#define ROWS  (BATCH*SEQ)   // 2048
#define CH    32            // chunk length for parallel scan
#define NCH   (SEQ/CH)      // 32 chunks
#define NSPLIT 8            // G2 split-K factor

typedef unsigned short u16;
typedef __bf16 bf16x8 __attribute__((ext_vector_type(8)));
typedef float  f32x4  __attribute__((ext_vector_type(4)));

__device__ __forceinline__ float bf2f(u16 v) {
    return __uint_as_float(((unsigned)v) << 16);
}
__device__ __forceinline__ u16 f2bf(float f) {
    unsigned u = __float_as_uint(f);
    return (u16)((u + 0x7FFFu + ((u >> 16) & 1u)) >> 16);
}

// global -> LDS direct DMA, 16B per lane. LDS dest = wave-uniform base + lane*16.
__device__ __forceinline__ void gload16(const void* g, const void* l) {
    __builtin_amdgcn_global_load_lds(
        (const __attribute__((address_space(1))) unsigned int*)(uintptr_t)g,
        (__attribute__((address_space(3))) unsigned int*)(uintptr_t)l,
        16, 0, 0);
}

// ---------------------------------------------------------------------------
// bf16 MFMA GEMM: C[M,N] += A[M,K] @ B[K,N], A row-major bf16, BT = B^T
// [Npad][K] row-major bf16. C fp32 [*, ldc]. 128x128 tile, BK=32, 4 waves.
// Optional split-K over blockIdx.z (each z does Ksplit, writes its own C slab).
// Requires M%128==0, Npad%128==0, Ksplit%32==0.
// ---------------------------------------------------------------------------
__global__ __launch_bounds__(256) void gemm_bf16(
    const u16* __restrict__ A,
    const u16* __restrict__ BT,
    float* __restrict__ C, int ldc,
    int N, int Ksplit, long long zCstride)
{
    __shared__ u16 As[128 * 32];
    __shared__ u16 Bs[128 * 32];

    const int K = (int)gridDim.z * Ksplit;     // full K (A/BT leading dim)
    int tid  = threadIdx.x;
    int lane = tid & 63, wid = tid >> 6;
    int wr = wid >> 1, wc = wid & 1;
    int row0 = blockIdx.y * 128, col0 = blockIdx.x * 128;
    int kbeg = blockIdx.z * Ksplit, kend = kbeg + Ksplit;

    // staging coords: each wave stages 32 rows of A-tile and 32 rows of BT-tile
    int sRow = wid * 32 + (lane >> 2);      // +c*16
    int sOff = (lane & 3) * 8;              // k elements within row

    const u16* Abase = A  + (size_t)(row0 + sRow) * K + sOff;
    const u16* Bbase = BT + (size_t)(col0 + sRow) * K + sOff;

    // fragment coords
    int frow = lane & 15;
    int fk   = (lane >> 4) * 8;

    f32x4 acc[4][4] = {};

    for (int k0 = kbeg; k0 < kend; k0 += 32) {
        #pragma unroll
        for (int c = 0; c < 2; ++c) {
            gload16(Abase + (size_t)c * 16 * K + k0, As + (wid * 32 + c * 16) * 32);
            gload16(Bbase + (size_t)c * 16 * K + k0, Bs + (wid * 32 + c * 16) * 32);
        }
        __syncthreads();   // drains vmcnt -> LDS tiles ready

        bf16x8 af[4], bfr[4];
        #pragma unroll
        for (int m = 0; m < 4; ++m)
            af[m] = *(const bf16x8*)(As + (wr * 64 + m * 16 + frow) * 32 + fk);
        #pragma unroll
        for (int n = 0; n < 4; ++n)
            bfr[n] = *(const bf16x8*)(Bs + (wc * 64 + n * 16 + frow) * 32 + fk);
        #pragma unroll
        for (int m = 0; m < 4; ++m)
            #pragma unroll
            for (int n = 0; n < 4; ++n)
                acc[m][n] = __builtin_amdgcn_mfma_f32_16x16x32_bf16(
                    af[m], bfr[n], acc[m][n], 0, 0, 0);
        __syncthreads();   // all reads done before next stage overwrites
    }

    // epilogue: C/D layout col=lane&15, row=(lane>>4)*4+reg  [m89-verified]
    size_t zoff = (size_t)blockIdx.z * (size_t)zCstride;
    int orow = row0 + wr * 64 + (lane >> 4) * 4;
    int ocol = col0 + wc * 64 + (lane & 15);
    #pragma unroll
    for (int m = 0; m < 4; ++m)
        #pragma unroll
        for (int n = 0; n < 4; ++n) {
            int colb = ocol + n * 16;
            if (colb < N) {
                #pragma unroll
                for (int r = 0; r < 4; ++r)
                    C[zoff + (size_t)(orow + m * 16 + r) * ldc + colb] = acc[m][n][r];
            }
        }
}

// ---------------------------------------------------------------------------
// Transpose-cast: in [K][N] fp32 -> out [Npad][K] bf16, zero-fill n >= N.
// ---------------------------------------------------------------------------
__global__ __launch_bounds__(256) void tcast_kernel(
    const float* __restrict__ in, u16* __restrict__ outp,
    int K, int N, int Npad)
{
    __shared__ float tile[32][33];
    int tx = threadIdx.x & 31;
    int ty = threadIdx.x >> 5;
    int k0 = blockIdx.y * 32, n0 = blockIdx.x * 32;
    #pragma unroll
    for (int i = 0; i < 4; ++i) {
        int k = k0 + ty + i * 8, n = n0 + tx;
        tile[ty + i * 8][tx] = (k < K && n < N) ? in[(size_t)k * N + n] : 0.f;
    }
    __syncthreads();
    #pragma unroll
    for (int i = 0; i < 4; ++i) {
        int n = n0 + ty + i * 8, k = k0 + tx;
        if (n < Npad && k < K)
            outp[(size_t)n * K + k] = f2bf(tile[tx][ty + i * 8]);
    }
}

// plain cast fp32 -> bf16, n % 4 == 0
__global__ __launch_bounds__(256) void cast_kernel(
    const float* __restrict__ in, u16* __restrict__ outp, int n)
{
    int i = (blockIdx.x * 256 + threadIdx.x) * 4;
    if (i < n) {
        float4 v = *(const float4*)(in + i);
        outp[i + 0] = f2bf(v.x); outp[i + 1] = f2bf(v.y);
        outp[i + 2] = f2bf(v.z); outp[i + 3] = f2bf(v.w);
    }
}

// G2 split-K reduce: xdbl = sum_z Xpart[z]
__global__ __launch_bounds__(256) void reduce_split_kernel(
    const float* __restrict__ part, float* __restrict__ outp)
{
    int i = blockIdx.x * 256 + threadIdx.x;
    if (i < ROWS * 96) {
        float s = 0.f;
        #pragma unroll
        for (int z = 0; z < NSPLIT; ++z) s += part[(size_t)z * ROWS * 96 + i];
        outp[i] = s;
    }
}

// ---------------------------------------------------------------------------
// fp32 tiled GEMM (kept for G3 only): C = softplus(A@B + bias)
// ---------------------------------------------------------------------------
template<int ACT>
__global__ __launch_bounds__(256) void gemm_f32(
    const float* __restrict__ A, int lda,
    const float* __restrict__ B, int ldb,
    float* __restrict__ C, int ldc,
    int M, int N, int K,
    const float* __restrict__ bias)
{
    const int BM = 64, BN = 64, BK = 16;
    __shared__ float As[BK][BM];
    __shared__ float Bs[BK][BN];

    int tid  = threadIdx.x;
    int row0 = blockIdx.y * BM;
    int col0 = blockIdx.x * BN;
    int tx = tid & 15;
    int ty = tid >> 4;
    int ar = tid >> 2;
    int ac = (tid & 3) * 4;
    int br = tid >> 4;
    int bc = (tid & 15) * 4;

    float acc[4][4] = {};

    for (int k0 = 0; k0 < K; k0 += BK) {
        #pragma unroll
        for (int j = 0; j < 4; ++j)
            As[ac + j][ar] = A[(size_t)(row0 + ar) * lda + k0 + ac + j];
        #pragma unroll
        for (int j = 0; j < 4; ++j) {
            int c = col0 + bc + j;
            Bs[br][bc + j] = (c < N) ? B[(size_t)(k0 + br) * ldb + c] : 0.f;
        }
        __syncthreads();
        #pragma unroll
        for (int k = 0; k < BK; ++k) {
            float4 a4 = *(const float4*)&As[k][ty * 4];
            float4 b4 = *(const float4*)&Bs[k][tx * 4];
            float av[4] = {a4.x, a4.y, a4.z, a4.w};
            float bv[4] = {b4.x, b4.y, b4.z, b4.w};
            #pragma unroll
            for (int i = 0; i < 4; ++i)
                #pragma unroll
                for (int j = 0; j < 4; ++j)
                    acc[i][j] = fmaf(av[i], bv[j], acc[i][j]);
        }
        __syncthreads();
    }

    #pragma unroll
    for (int i = 0; i < 4; ++i) {
        int r = row0 + ty * 4 + i;
        #pragma unroll
        for (int j = 0; j < 4; ++j) {
            int c = col0 + tx * 4 + j;
            if (c < N) {
                float v = acc[i][j];
                if (bias) v += bias[c];
                if (ACT == 1) v = (v > 20.f) ? v : log1pf(expf(v));
                C[(size_t)r * ldc + c] = v;
            }
        }
    }
}

// ---------------------------------------------------------------------------
// Depthwise causal conv (k=3) + SiLU -> bf16 u
// ---------------------------------------------------------------------------
__global__ __launch_bounds__(256) void conv_silu_kernel(
    const float* __restrict__ xw,
    const float* __restrict__ Wc,
    u16* __restrict__ u)
{
    int idx = blockIdx.x * 256 + threadIdx.x;
    if (idx >= ROWS * DI) return;
    int d = idx & (DI - 1);
    int r = idx >> 11;
    int l = r & (SEQ - 1);
    float w0 = Wc[d * 3 + 0], w1 = Wc[d * 3 + 1], w2 = Wc[d * 3 + 2];
    const float* base = xw + (size_t)r * 4096 + d;
    float v = w2 * base[0];
    if (l >= 1) v += w1 * base[-4096];
    if (l >= 2) v += w0 * base[-8192];
    v = v / (1.f + expf(-v));
    u[(size_t)r * DI + d] = f2bf(v);
}

// ---------------------------------------------------------------------------
// Scan pass A: per (b, chunk, d) thread; P = prod(dA), Q = local h from 0.
// ---------------------------------------------------------------------------
__global__ __launch_bounds__(256) void scan_chunk_kernel(
    const float* __restrict__ delta,
    const u16*  __restrict__ u,
    const float* __restrict__ xdbl,
    const float* __restrict__ A_log,
    float* __restrict__ P,
    float* __restrict__ Q)
{
    int idx = blockIdx.x * 256 + threadIdx.x;   // B*NCH*DI
    int d = idx & (DI - 1);
    int rc = idx >> 11;
    int chunk = rc & (NCH - 1);
    int b = rc >> 5;

    float Av[DS], h[DS], Pp[DS];
    #pragma unroll
    for (int q = 0; q < 4; ++q) {
        float4 a4 = *(const float4*)(A_log + (size_t)d * DS + q * 4);
        Av[q*4+0] = -__expf(a4.x); Av[q*4+1] = -__expf(a4.y);
        Av[q*4+2] = -__expf(a4.z); Av[q*4+3] = -__expf(a4.w);
    }
    #pragma unroll
    for (int n = 0; n < DS; ++n) { h[n] = 0.f; Pp[n] = 1.f; }

    int l0 = chunk * CH;
    const float* drow = delta + ((size_t)b * SEQ + l0) * DI + d;
    const u16*  urow  = u     + ((size_t)b * SEQ + l0) * DI + d;
    const float* xrow = xdbl  + ((size_t)b * SEQ + l0) * 96 + 64;

    #pragma unroll 4
    for (int l = 0; l < CH; ++l) {
        float dv = drow[(size_t)l * DI];
        float du = dv * bf2f(urow[(size_t)l * DI]);
        float Bv[DS];
        #pragma unroll
        for (int q = 0; q < 4; ++q) {
            float4 b4 = *(const float4*)(xrow + l * 96 + q * 4);
            Bv[q*4+0] = b4.x; Bv[q*4+1] = b4.y; Bv[q*4+2] = b4.z; Bv[q*4+3] = b4.w;
        }
        #pragma unroll
        for (int n = 0; n < DS; ++n) {
            float dA = __expf(dv * Av[n]);
            h[n] = dA * h[n] + du * Bv[n];
            Pp[n] *= dA;
        }
    }
    float* Pd = P + (size_t)idx * DS;
    float* Qd = Q + (size_t)idx * DS;
    #pragma unroll
    for (int n = 0; n < DS; ++n) { Pd[n] = Pp[n]; Qd[n] = h[n]; }
}

// ---------------------------------------------------------------------------
// Scan pass B: sequential combine over chunks; hin written IN PLACE over Q.
// ---------------------------------------------------------------------------
__global__ __launch_bounds__(256) void scan_combine_kernel(
    const float* __restrict__ P,
    float* __restrict__ Q)          // in: Q, out: hin
{
    int idx = blockIdx.x * 256 + threadIdx.x;    // B*DI*DS
    int nd = idx & (DI * DS - 1);
    int b = idx >> 15;
    float h = 0.f;
    for (int c = 0; c < NCH; ++c) {
        size_t off = (size_t)(b * NCH + c) * DI * DS + nd;
        float p = P[off], q = Q[off];
        Q[off] = h;
        h = p * h + q;
    }
}

// ---------------------------------------------------------------------------
// Scan pass C: local scan with correct h_in, emit y into buf0 cols 0..2047.
// ---------------------------------------------------------------------------
__global__ __launch_bounds__(256) void scan_final_kernel(
    const float* __restrict__ delta,
    const u16*  __restrict__ u,
    const float* __restrict__ xdbl,
    const float* __restrict__ A_log,
    const float* __restrict__ hin,
    float* __restrict__ ybuf)
{
    int idx = blockIdx.x * 256 + threadIdx.x;   // B*NCH*DI
    int d = idx & (DI - 1);
    int rc = idx >> 11;
    int chunk = rc & (NCH - 1);
    int b = rc >> 5;

    float Av[DS], h[DS];
    #pragma unroll
    for (int q = 0; q < 4; ++q) {
        float4 a4 = *(const float4*)(A_log + (size_t)d * DS + q * 4);
        Av[q*4+0] = -__expf(a4.x); Av[q*4+1] = -__expf(a4.y);
        Av[q*4+2] = -__expf(a4.z); Av[q*4+3] = -__expf(a4.w);
    }
    const float* hsrc = hin + (size_t)idx * DS;
    #pragma unroll
    for (int n = 0; n < DS; ++n) h[n] = hsrc[n];

    int l0 = chunk * CH;
    const float* drow = delta + ((size_t)b * SEQ + l0) * DI + d;
    const u16*  urow  = u     + ((size_t)b * SEQ + l0) * DI + d;
    const float* xrow = xdbl  + ((size_t)b * SEQ + l0) * 96 + 64;
    float* yrow = ybuf + ((size_t)b * SEQ + l0) * 4096 + d;

    #pragma unroll 4
    for (int l = 0; l < CH; ++l) {
        float dv = drow[(size_t)l * DI];
        float du = dv * bf2f(urow[(size_t)l * DI]);
        float Bv[DS], Cv[DS];
        #pragma unroll
        for (int q = 0; q < 4; ++q) {
            float4 b4 = *(const float4*)(xrow + l * 96 + q * 4);
            Bv[q*4+0] = b4.x; Bv[q*4+1] = b4.y; Bv[q*4+2] = b4.z; Bv[q*4+3] = b4.w;
            float4 c4 = *(const float4*)(xrow + l * 96 + 16 + q * 4);
            Cv[q*4+0] = c4.x; Cv[q*4+1] = c4.y; Cv[q*4+2] = c4.z; Cv[q*4+3] = c4.w;
        }
        float y = 0.f;
        #pragma unroll
        for (int n = 0; n < DS; ++n) {
            float dA = __expf(dv * Av[n]);
            h[n] = dA * h[n] + du * Bv[n];
            y = fmaf(h[n], Cv[n], y);
        }
        yrow[(size_t)l * 4096] = y;
    }
}

// ---------------------------------------------------------------------------
// y_final(bf16) = (y_ssm + u*D) * silu(res)
// ---------------------------------------------------------------------------
__global__ __launch_bounds__(256) void combine_kernel(
    const float* __restrict__ buf0,
    const u16*  __restrict__ u,
    const float* __restrict__ Dp,
    u16* __restrict__ yf)
{
    int idx = blockIdx.x * 256 + threadIdx.x;
    if (idx >= ROWS * DI) return;
    int d = idx & (DI - 1);
    int r = idx >> 11;
    float ys = buf0[(size_t)r * 4096 + d];
    float rs = buf0[(size_t)r * 4096 + 2048 + d];
    float uv = bf2f(u[(size_t)r * DI + d]);
    float v = (ys + uv * Dp[d]) * (rs / (1.f + expf(-rs)));
    yf[(size_t)r * DI + d] = f2bf(v);
}

extern "C" void kernel_launch(void* const* d_in, const int* in_sizes, int n_in,
                              void* d_out, int out_size, void* d_ws, size_t ws_size,
                              hipStream_t stream) {
    const float* x       = (const float*)d_in[0];
    const float* W_in    = (const float*)d_in[1];
    const float* W_conv  = (const float*)d_in[2];
    const float* W_x     = (const float*)d_in[3];
    const float* W_dt    = (const float*)d_in[4];
    const float* b_dt    = (const float*)d_in[5];
    const float* A_log   = (const float*)d_in[6];
    const float* D_param = (const float*)d_in[7];
    const float* W_out   = (const float*)d_in[8];
    float* out = (float*)d_out;

    // workspace layout (bytes): tight reuse, total ~77.3 MB
    float* buf0  = (float*)d_ws;                    // 32MB  [2048][4096] xW_in; y_ssm cols 0..2047
    float* delta = buf0 + (size_t)ROWS * 4096;      // 16MB  [2048][2048]
    float* Qbuf  = delta + (size_t)ROWS * DI;       // 8MB   Q -> hin -> yf(bf16)
    float* R1    = Qbuf + (size_t)BATCH * NCH * DI * DS;  // 8MB  WinT -> Xpart -> P
    float* R2    = R1 + 2 * 1024 * 1024;            // 4MB   xbf -> WoutT
    float* xdbl  = R2 + 1024 * 1024;                // 0.75MB [2048][96]
    u16*  u_bf   = (u16*)(xdbl + (size_t)ROWS * 96);// 8MB   [2048][2048] bf16
    u16*  WxT    = (u16*)(u_bf + (size_t)ROWS * DI);// 0.5MB [128][2048] bf16 (padded)

    u16* WinT  = (u16*)R1;   float* Xpart = R1;   float* P = R1;
    u16* xbf   = (u16*)R2;   u16* WoutT = (u16*)R2;
    u16* yf    = (u16*)Qbuf;

    dim3 blk(256);

    // weight transposes / casts
    tcast_kernel<<<dim3(4096/32, 1024/32), blk, 0, stream>>>(W_in, WinT, 1024, 4096, 4096);
    cast_kernel<<<(ROWS * DM / 4 + 255) / 256, blk, 0, stream>>>(x, xbf, ROWS * DM);

    // G1: buf0 = x @ W_in   [2048 x 4096], K=1024
    gemm_bf16<<<dim3(4096/128, ROWS/128, 1), blk, 0, stream>>>(
        xbf, WinT, buf0, 4096, 4096, 1024, 0);

    // W_out^T (R2 free after G1), W_x^T
    tcast_kernel<<<dim3(1024/32, 2048/32), blk, 0, stream>>>(W_out, WoutT, 2048, 1024, 1024);
    tcast_kernel<<<dim3(128/32, 2048/32), blk, 0, stream>>>(W_x, WxT, 2048, 96, 128);

    // conv + silu -> u (bf16)
    conv_silu_kernel<<<(ROWS * DI) / 256, blk, 0, stream>>>(buf0, W_conv, u_bf);

    // G2: x_dbl = u @ W_x   split-K=8 -> Xpart, then reduce
    gemm_bf16<<<dim3(1, ROWS/128, NSPLIT), blk, 0, stream>>>(
        u_bf, WxT, Xpart, 96, 96, DI / NSPLIT, (long long)ROWS * 96);
    reduce_split_kernel<<<(ROWS * 96 + 255) / 256, blk, 0, stream>>>(Xpart, xdbl);

    // G3: delta = softplus(dt @ W_dt + b_dt)  [2048 x 2048], K=64 (fp32)
    gemm_f32<1><<<dim3(DI / 64, ROWS / 64), blk, 0, stream>>>(
        xdbl, 96, W_dt, DI, delta, DI, ROWS, DI, DTR, b_dt);

    // scan passes
    scan_chunk_kernel<<<(BATCH * NCH * DI) / 256, blk, 0, stream>>>(
        delta, u_bf, xdbl, A_log, P, Qbuf);
    scan_combine_kernel<<<(BATCH * DI * DS) / 256, blk, 0, stream>>>(P, Qbuf);
    scan_final_kernel<<<(BATCH * NCH * DI) / 256, blk, 0, stream>>>(
        delta, u_bf, xdbl, A_log, Qbuf, buf0);

    // combine -> y_final (bf16, overwrites Q region after scan C consumed it)
    combine_kernel<<<(ROWS * DI) / 256, blk, 0, stream>>>(buf0, u_bf, D_param, yf);

    // G4: out = y_final @ W_out   [2048 x 1024], K=2048
    gemm_bf16<<<dim3(1024/128, ROWS/128, 1), blk, 0, stream>>>(
        yf, WoutT, out, 1024, 1024, 2048, 0);
}